// Round 2
// baseline (448.530 us; speedup 1.0000x reference)
//
#include <hip/hip_runtime.h>
#include <stdint.h>

#define HH 64
#define WW 64
#define AA 9
#define N_PER (HH*WW*AA)   // 36864
#define NSORT 65536
#define NB 4
#define PRE_NMS 6000
#define POST_NMS 300
#define JWORDS 94          // ceil(6000/64)
#define NMS_THRESH 0.7f
#define FEAT_STRIDE 16
#define TILE 2048

// ---------------- Phase 1: decode boxes + build sort keys ----------------
__global__ void proposal_kernel(const float* __restrict__ scores,
                                const float* __restrict__ deltas,
                                const float* __restrict__ img_info,
                                const float* __restrict__ anchors,
                                float* __restrict__ props,       // NB*N_PER*4
                                uint64_t* __restrict__ keys)     // NB*NSORT
{
#pragma clang fp contract(off)
    int tid = blockIdx.x * blockDim.x + threadIdx.x;
    int b = tid >> 16;
    int i = tid & 65535;
    if (b >= NB) return;
    if (i >= N_PER) { keys[(size_t)b*NSORT + i] = 0ull; return; }
    int a = i % AA;
    int s = i / AA;
    int w = s % WW;
    int h = s / WW;
    float sx = (float)(w * FEAT_STRIDE);
    float sy = (float)(h * FEAT_STRIDE);
    float ax1 = anchors[a*4+0] + sx;
    float ay1 = anchors[a*4+1] + sy;
    float ax2 = anchors[a*4+2] + sx;
    float ay2 = anchors[a*4+3] + sy;
    float width  = ax2 - ax1 + 1.0f;
    float height = ay2 - ay1 + 1.0f;
    float cx = ax1 + 0.5f * width;
    float cy = ay1 + 0.5f * height;
    size_t base = ((size_t)b*36 + a*4) * (HH*WW) + (size_t)h*WW + w;
    float dx = deltas[base];
    float dy = deltas[base + HH*WW];
    float dw = deltas[base + 2*HH*WW];
    float dh = deltas[base + 3*HH*WW];
    float pcx = dx * width + cx;
    float pcy = dy * height + cy;
    float pw = (float)exp((double)dw) * width;   // correctly-rounded f32 exp
    float ph = (float)exp((double)dh) * height;
    float x1 = pcx - 0.5f * pw;
    float y1 = pcy - 0.5f * ph;
    float x2 = pcx + 0.5f * pw;
    float y2 = pcy + 0.5f * ph;
    float maxx = img_info[1] - 1.0f;
    float maxy = img_info[0] - 1.0f;
    x1 = fminf(fmaxf(x1, 0.0f), maxx);
    y1 = fminf(fmaxf(y1, 0.0f), maxy);
    x2 = fminf(fmaxf(x2, 0.0f), maxx);
    y2 = fminf(fmaxf(y2, 0.0f), maxy);
    float4* pp = (float4*)(props + ((size_t)b*N_PER + i)*4);
    *pp = make_float4(x1, y1, x2, y2);
    float sc = scores[((size_t)b*18 + 9 + a) * (HH*WW) + (size_t)h*WW + w];
    uint32_t u = __float_as_uint(sc);
    u = (u & 0x80000000u) ? ~u : (u | 0x80000000u);   // monotonic float->uint
    uint64_t key = ((uint64_t)u << 32) | (uint32_t)(~(uint32_t)i);
    keys[(size_t)b*NSORT + i] = key;
}

// ---------------- Phase 2: bitonic sort (descending) ----------------
__global__ void __launch_bounds__(1024) bitonic_local_sort(uint64_t* keys) {
    __shared__ uint64_t sk[TILE];
    int tile = blockIdx.x;
    uint64_t* base = keys + (size_t)tile * TILE;
    int lt = threadIdx.x;
    sk[lt] = base[lt];
    sk[lt + 1024] = base[lt + 1024];
    __syncthreads();
    int gbase = (tile & (NSORT/TILE - 1)) * TILE;   // per-image element offset
    for (int size = 2; size <= TILE; size <<= 1) {
        for (int stride = size >> 1; stride > 0; stride >>= 1) {
            int idx = ((lt & ~(stride-1)) << 1) | (lt & (stride-1));
            int partner = idx | stride;
            int gi = gbase + idx;
            bool up = (gi & size) == 0;  // descending overall
            uint64_t x = sk[idx], y = sk[partner];
            if (up ? (x < y) : (x > y)) { sk[idx] = y; sk[partner] = x; }
            __syncthreads();
        }
    }
    base[lt] = sk[lt];
    base[lt + 1024] = sk[lt + 1024];
}

__global__ void bitonic_global_pass(uint64_t* keys, int size, int stride) {
    int tid = blockIdx.x * blockDim.x + threadIdx.x;  // NB*NSORT/2 pairs
    int img = tid >> 15;
    int p = tid & 32767;
    int idx = ((p & ~(stride-1)) << 1) | (p & (stride-1));
    int partner = idx | stride;
    bool up = (idx & size) == 0;
    uint64_t* base = keys + (size_t)img * NSORT;
    uint64_t x = base[idx], y = base[partner];
    if (up ? (x < y) : (x > y)) { base[idx] = y; base[partner] = x; }
}

__global__ void __launch_bounds__(1024) bitonic_local_tail(uint64_t* keys, int size) {
    __shared__ uint64_t sk[TILE];
    int tile = blockIdx.x;
    uint64_t* base = keys + (size_t)tile * TILE;
    int lt = threadIdx.x;
    sk[lt] = base[lt]; sk[lt+1024] = base[lt+1024];
    __syncthreads();
    int gbase = (tile & (NSORT/TILE - 1)) * TILE;
    bool up = ((gbase & size) == 0);  // uniform per tile (size > TILE)
    for (int stride = TILE/2; stride > 0; stride >>= 1) {
        int idx = ((lt & ~(stride-1)) << 1) | (lt & (stride-1));
        int partner = idx | stride;
        uint64_t x = sk[idx], y = sk[partner];
        if (up ? (x < y) : (x > y)) { sk[idx] = y; sk[partner] = x; }
        __syncthreads();
    }
    base[lt] = sk[lt]; base[lt+1024] = sk[lt+1024];
}

// ---------------- Phase 3: gather top-6000 boxes ----------------
__global__ void gather_top(const uint64_t* __restrict__ keys,
                           const float* __restrict__ props,
                           float* __restrict__ topb) {
    int tid = blockIdx.x*blockDim.x + threadIdx.x;
    if (tid >= NB*PRE_NMS) return;
    int b = tid / PRE_NMS;
    int k = tid - b*PRE_NMS;
    uint64_t key = keys[(size_t)b*NSORT + k];
    uint32_t idx = ~(uint32_t)(key & 0xFFFFFFFFu);
    const float4 box = *(const float4*)(props + ((size_t)b*N_PER + idx)*4);
    *(float4*)(topb + (size_t)tid*4) = box;
}

// ---------------- Phase 4: NMS suppression bitmask ----------------
__global__ void __launch_bounds__(64) nms_mask(const float* __restrict__ topb,
                                               uint64_t* __restrict__ mask) {
#pragma clang fp contract(off)
    int jblock = blockIdx.x;  // 0..93
    int iblock = blockIdx.y;  // 0..93
    int b = blockIdx.z;
    int t = threadIdx.x;      // 0..63
    __shared__ float4 jb[64];
    int j0 = jblock*64;
    int jcount = min(64, PRE_NMS - j0);
    if (t < jcount) jb[t] = *(const float4*)(topb + ((size_t)b*PRE_NMS + j0 + t)*4);
    __syncthreads();
    int i = iblock*64 + t;
    if (i >= PRE_NMS) return;
    float4 bi = *(const float4*)(topb + ((size_t)b*PRE_NMS + i)*4);
    float wi = bi.z - bi.x + 1.0f;
    float hi_ = bi.w - bi.y + 1.0f;
    float areai = wi * hi_;
    uint64_t bits = 0;
    for (int jj = 0; jj < jcount; ++jj) {
        float4 bj = jb[jj];
        float xx1 = fmaxf(bi.x, bj.x);
        float yy1 = fmaxf(bi.y, bj.y);
        float xx2 = fminf(bi.z, bj.z);
        float yy2 = fminf(bi.w, bj.w);
        float iw = fmaxf(0.0f, xx2 - xx1 + 1.0f);
        float ih = fmaxf(0.0f, yy2 - yy1 + 1.0f);
        float inter = iw * ih;
        float wj = bj.z - bj.x + 1.0f;
        float hj = bj.w - bj.y + 1.0f;
        float areaj = wj * hj;
        float denom = (areai + areaj) - inter;
        float iou = inter / denom;
        if (iou > NMS_THRESH) bits |= (1ull << jj);
    }
    mask[((size_t)b*PRE_NMS + i)*JWORDS + jblock] = bits;
}

// ---------------- Phase 5: sequential greedy scan + output ----------------
__global__ void __launch_bounds__(64) nms_scan(const uint64_t* __restrict__ mask,
                                               const float* __restrict__ topb,
                                               float* __restrict__ out) {
    int b = blockIdx.x;
    int t = threadIdx.x;
    __shared__ uint64_t remv[JWORDS];
    __shared__ int keep[POST_NMS];
    remv[t] = 0ull;
    if (t < JWORDS - 64) remv[t + 64] = 0ull;
    __syncthreads();
    int nkeep = 0;
    int i = 0;
    while (i < PRE_NMS && nkeep < POST_NMS) {
        int w = i >> 6;
        uint64_t rv = remv[w];
        uint64_t live = ~rv & (~0ull << (i & 63));
        if (w == JWORDS-1) live &= ((1ull << 48) - 1);  // 6000 = 93*64 + 48
        if (live == 0ull) { i = (w + 1) << 6; continue; }
        int bit = __ffsll((unsigned long long)live) - 1;
        i = (w << 6) | bit;
        if (t == 0) keep[nkeep] = i;
        nkeep++;
        if (nkeep >= POST_NMS) break;
        const uint64_t* row = mask + ((size_t)b*PRE_NMS + i)*JWORDS;
        remv[t] |= row[t];
        if (t < JWORDS - 64) remv[t + 64] |= row[t + 64];
        __syncthreads();
        i++;
    }
    __syncthreads();
    for (int k = t; k < POST_NMS; k += 64) {
        float* o = out + ((size_t)b*POST_NMS + k)*5;
        o[0] = (float)b;
        if (k < nkeep) {
            int idx = keep[k];
            const float4 bx = *(const float4*)(topb + ((size_t)b*PRE_NMS + idx)*4);
            o[1] = bx.x; o[2] = bx.y; o[3] = bx.z; o[4] = bx.w;
        } else {
            o[1] = 0.0f; o[2] = 0.0f; o[3] = 0.0f; o[4] = 0.0f;
        }
    }
}

extern "C" void kernel_launch(void* const* d_in, const int* in_sizes, int n_in,
                              void* d_out, int out_size, void* d_ws, size_t ws_size,
                              hipStream_t stream) {
    const float* scores   = (const float*)d_in[0];
    const float* deltas   = (const float*)d_in[1];
    const float* img_info = (const float*)d_in[2];
    const float* anchors  = (const float*)d_in[3];
    float* out = (float*)d_out;

    uint8_t* ws = (uint8_t*)d_ws;
    float*    props = (float*)ws;                                   // 2,359,296 B
    uint64_t* keys  = (uint64_t*)(ws + 2359296);                    // 2,097,152 B
    float*    topb  = (float*)(ws + 2359296 + 2097152);             //   384,000 B
    uint64_t* mask  = (uint64_t*)(ws + 2359296 + 2097152 + 384000); // 18,048,000 B

    proposal_kernel<<<(NB*NSORT)/256, 256, 0, stream>>>(scores, deltas, img_info, anchors, props, keys);

    bitonic_local_sort<<<NB*NSORT/TILE, 1024, 0, stream>>>(keys);
    for (int size = 4096; size <= NSORT; size <<= 1) {
        for (int stride = size >> 1; stride >= TILE; stride >>= 1)
            bitonic_global_pass<<<(NB*NSORT/2)/256, 256, 0, stream>>>(keys, size, stride);
        bitonic_local_tail<<<NB*NSORT/TILE, 1024, 0, stream>>>(keys, size);
    }

    gather_top<<<(NB*PRE_NMS + 255)/256, 256, 0, stream>>>(keys, props, topb);

    dim3 mg(JWORDS, JWORDS, NB);
    nms_mask<<<mg, 64, 0, stream>>>(topb, mask);

    nms_scan<<<NB, 64, 0, stream>>>(mask, topb, out);
}